// Round 2
// baseline (1091.772 us; speedup 1.0000x reference)
//
#include <hip/hip_runtime.h>
#include <hip/hip_bf16.h>
#include <stdint.h>

#define HID 128

typedef __attribute__((ext_vector_type(8))) __bf16 bf16x8;
typedef __attribute__((ext_vector_type(4))) float f32x4;

static __device__ __forceinline__ float bf2f(ushort h){
  union { uint u; float f; } c; c.u = ((uint)h) << 16; return c.f;
}
static __device__ __forceinline__ ushort f2bf(float f){
  union { float f; uint u; } c; c.f = f;
  uint u = c.u;
  return (ushort)((u + 0x7fffu + ((u >> 16) & 1u)) >> 16);
}
static __device__ __forceinline__ bf16x8 load8(const ushort* p){
  return *(const bf16x8*)p;
}
static __device__ __forceinline__ bf16x8 pack8(float4 a, float4 b){
  union { ushort u[8]; bf16x8 v; } r;
  r.u[0]=f2bf(a.x); r.u[1]=f2bf(a.y); r.u[2]=f2bf(a.z); r.u[3]=f2bf(a.w);
  r.u[4]=f2bf(b.x); r.u[5]=f2bf(b.y); r.u[6]=f2bf(b.z); r.u[7]=f2bf(b.w);
  return r.v;
}

// ---------------- weight f32 -> bf16 convert ----------------
__global__ void k_cvt(const float* __restrict__ in, ushort* __restrict__ out, int n){
  int i = blockIdx.x * 256 + threadIdx.x;
  if (i < n) out[i] = f2bf(in[i]);
}

// ---------------- CSR build ----------------
__global__ void k_hist(const int* __restrict__ dst, int* __restrict__ cnt, int E){
  int e = blockIdx.x * 256 + threadIdx.x;
  if (e < E) atomicAdd(&cnt[dst[e]], 1);
}

__global__ void k_scan1(const int* __restrict__ cnt, int* __restrict__ offs,
                        int* __restrict__ bsums, int n){
  int gid = blockIdx.x * 1024 + threadIdx.x;
  int v = (gid < n) ? cnt[gid] : 0;
  int lane = threadIdx.x & 63, w = threadIdx.x >> 6;
  int x = v;
  #pragma unroll
  for (int d = 1; d < 64; d <<= 1){ int y = __shfl_up(x, d, 64); if (lane >= d) x += y; }
  __shared__ int tmp[16];
  if (lane == 63) tmp[w] = x;
  __syncthreads();
  if (threadIdx.x < 64){
    int s = (lane < 16) ? tmp[lane] : 0;
    #pragma unroll
    for (int d = 1; d < 16; d <<= 1){ int y = __shfl_up(s, d, 64); if (lane >= d) s += y; }
    if (lane < 16) tmp[lane] = s;
  }
  __syncthreads();
  int base = (w > 0) ? tmp[w - 1] : 0;
  int incl = base + x;
  if (gid < n) offs[gid] = incl - v;
  if (threadIdx.x == 1023) bsums[blockIdx.x] = incl;
}

__global__ void k_scan2(int* bsums, int nb){
  if (threadIdx.x == 0 && blockIdx.x == 0){
    int acc = 0;
    for (int i = 0; i < nb; i++){ int v = bsums[i]; bsums[i] = acc; acc += v; }
  }
}

__global__ void k_scan3(int* __restrict__ offs, const int* __restrict__ bsums, int n){
  int gid = blockIdx.x * 1024 + threadIdx.x;
  if (gid < n) offs[gid] += bsums[blockIdx.x];
}

__global__ void k_bucket(const int* __restrict__ src, const int* __restrict__ dst,
                         const int* __restrict__ offs, int* __restrict__ cursor,
                         int* __restrict__ csr, int E){
  int e = blockIdx.x * 256 + threadIdx.x;
  if (e < E){
    int d = dst[e];
    int p = atomicAdd(&cursor[d], 1);
    csr[offs[d] + p] = src[e];
  }
}

// ---------------- scatter-mean aggregation (wave per node) ----------------
// XF32=1: x is float32 (emb); XF32=0: x is bf16 (intermediates). agg out: bf16.
template<int XF32>
__global__ __launch_bounds__(256) void k_aggregate(
    const void* __restrict__ xv, const int* __restrict__ csr,
    const int* __restrict__ offs, const int* __restrict__ cnt,
    ushort* __restrict__ agg, int N){
  int node = blockIdx.x * 4 + (threadIdx.x >> 6);
  int lane = threadIdx.x & 63;
  if (node >= N) return;
  int beg = offs[node], d = cnt[node];
  float s0 = 0.f, s1 = 0.f;
  if (XF32){
    const float* x = (const float*)xv;
    for (int i = 0; i < d; i++){
      int sa = csr[beg + i];
      float2 v = *(const float2*)(x + (size_t)sa * HID + lane * 2);
      s0 += v.x; s1 += v.y;
    }
  } else {
    const ushort* x = (const ushort*)xv;
    for (int i = 0; i < d; i++){
      int sa = csr[beg + i];
      uint va = *(const uint*)(x + (size_t)sa * HID + lane * 2);
      s0 += bf2f((ushort)va); s1 += bf2f((ushort)(va >> 16));
    }
  }
  float inv = 1.0f / fmaxf((float)d, 1.0f);
  uint o = (uint)f2bf(s0 * inv) | ((uint)f2bf(s1 * inv) << 16);
  *(uint*)(agg + (size_t)node * HID + lane * 2) = o;
}

// ---------------- fused dual-GEMM + bias + LN + ReLU + residual ----------------
// xout = relu(LN(agg@Wl^T + xin@Wr^T + bl)) [+ xin if HAS_RES], stored bf16.
// C/D layout (m89-verified): col = lane&15, row = (lane>>4)*4 + reg.
// A layout: A[m = lane&15][k = quad*8 + j].
template<int XIN_F32, int HAS_RES>
__global__ __launch_bounds__(256) void k_layer(
    const ushort* __restrict__ agg, const void* __restrict__ xin_v,
    const ushort* __restrict__ Wl, const float* __restrict__ bl,
    const ushort* __restrict__ Wr,
    const float* __restrict__ gamma, const float* __restrict__ beta,
    ushort* __restrict__ xout, int N){
  int wv = threadIdx.x >> 6, lane = threadIdx.x & 63;
  int quad = lane >> 4, l16 = lane & 15;
  int rowbase = blockIdx.x * 64 + wv * 16;
  int arow = rowbase + l16;
  if (arow >= N) arow = N - 1;   // clamp: C row m only depends on A row m

  bf16x8 a1[4], a2[4];
  #pragma unroll
  for (int k = 0; k < 4; k++){
    int off = k * 32 + quad * 8;
    a1[k] = load8(agg + (size_t)arow * HID + off);
    if (XIN_F32){
      const float* xf = (const float*)xin_v;
      float4 p0 = *(const float4*)(xf + (size_t)arow * HID + off);
      float4 p1 = *(const float4*)(xf + (size_t)arow * HID + off + 4);
      a2[k] = pack8(p0, p1);
    } else {
      a2[k] = load8((const ushort*)xin_v + (size_t)arow * HID + off);
    }
  }

  f32x4 acc[8];
  #pragma unroll
  for (int jt = 0; jt < 8; jt++){
    int j = jt * 16 + l16;
    f32x4 c = {0.f, 0.f, 0.f, 0.f};
    #pragma unroll
    for (int k = 0; k < 4; k++){
      bf16x8 b = load8(Wl + (size_t)j * HID + k * 32 + quad * 8);
      c = __builtin_amdgcn_mfma_f32_16x16x32_bf16(a1[k], b, c, 0, 0, 0);
    }
    #pragma unroll
    for (int k = 0; k < 4; k++){
      bf16x8 b = load8(Wr + (size_t)j * HID + k * 32 + quad * 8);
      c = __builtin_amdgcn_mfma_f32_16x16x32_bf16(a2[k], b, c, 0, 0, 0);
    }
    float bias = bl[j];
    c[0] += bias; c[1] += bias; c[2] += bias; c[3] += bias;
    acc[jt] = c;
  }

  // LayerNorm over 128 cols per row; quad's 16 lanes hold one row's cols per jt
  float s1[4] = {0,0,0,0}, s2[4] = {0,0,0,0};
  #pragma unroll
  for (int jt = 0; jt < 8; jt++){
    #pragma unroll
    for (int r = 0; r < 4; r++){ float v = acc[jt][r]; s1[r] += v; s2[r] += v * v; }
  }
  #pragma unroll
  for (int m = 1; m < 16; m <<= 1){
    #pragma unroll
    for (int r = 0; r < 4; r++){
      s1[r] += __shfl_xor(s1[r], m, 64);
      s2[r] += __shfl_xor(s2[r], m, 64);
    }
  }
  float mu[4], rs[4];
  #pragma unroll
  for (int r = 0; r < 4; r++){
    mu[r] = s1[r] * (1.f / 128.f);
    float var = s2[r] * (1.f / 128.f) - mu[r] * mu[r];
    rs[r] = rsqrtf(var + 1e-5f);
  }

  #pragma unroll
  for (int jt = 0; jt < 8; jt++){
    int col = jt * 16 + l16;
    float g = gamma[col], bb = beta[col];
    #pragma unroll
    for (int r = 0; r < 4; r++){
      int row = rowbase + quad * 4 + r;
      if (row < N){
        float v = (acc[jt][r] - mu[r]) * rs[r] * g + bb;
        v = fmaxf(v, 0.f);
        if (HAS_RES) v += bf2f(((const ushort*)xin_v)[(size_t)row * HID + col]);
        xout[(size_t)row * HID + col] = f2bf(v);
      }
    }
  }
}

// ---------------- JK: out = [emb,x1,x2,x3] @ jkW^T + jkb  (out: float32) ----------------
__global__ __launch_bounds__(256) void k_jk(
    const float* __restrict__ emb, const ushort* __restrict__ x1,
    const ushort* __restrict__ x2, const ushort* __restrict__ x3,
    const ushort* __restrict__ jkW, const float* __restrict__ jkb,
    float* __restrict__ out, int N){
  int wv = threadIdx.x >> 6, lane = threadIdx.x & 63;
  int quad = lane >> 4, l16 = lane & 15;
  int rowbase = blockIdx.x * 64 + wv * 16;
  int arow = rowbase + l16;
  if (arow >= N) arow = N - 1;

  bf16x8 a[16];
  #pragma unroll
  for (int kk = 0; kk < 4; kk++){
    int off = kk * 32 + quad * 8;
    float4 p0 = *(const float4*)(emb + (size_t)arow * HID + off);
    float4 p1 = *(const float4*)(emb + (size_t)arow * HID + off + 4);
    a[kk] = pack8(p0, p1);
  }
  const ushort* bs[3] = {x1, x2, x3};
  #pragma unroll
  for (int s = 0; s < 3; s++){
    #pragma unroll
    for (int kk = 0; kk < 4; kk++){
      a[4 + s * 4 + kk] = load8(bs[s] + (size_t)arow * HID + kk * 32 + quad * 8);
    }
  }
  #pragma unroll
  for (int jt = 0; jt < 8; jt++){
    int j = jt * 16 + l16;
    f32x4 c = {0.f, 0.f, 0.f, 0.f};
    #pragma unroll
    for (int kk = 0; kk < 16; kk++){
      bf16x8 b = load8(jkW + (size_t)j * 512 + kk * 32 + quad * 8);
      c = __builtin_amdgcn_mfma_f32_16x16x32_bf16(a[kk], b, c, 0, 0, 0);
    }
    float bias = jkb[j];
    #pragma unroll
    for (int r = 0; r < 4; r++){
      int row = rowbase + quad * 4 + r;
      if (row < N)
        out[(size_t)row * HID + jt * 16 + l16] = c[r] + bias;
    }
  }
}

extern "C" void kernel_launch(void* const* d_in, const int* in_sizes, int n_in,
                              void* d_out, int out_size, void* d_ws, size_t ws_size,
                              hipStream_t stream){
  const float* emb   = (const float*)d_in[0];
  const float* Wl    = (const float*)d_in[1];
  const float* bl    = (const float*)d_in[2];
  const float* Wr    = (const float*)d_in[3];
  const float* gamma = (const float*)d_in[4];
  const float* beta  = (const float*)d_in[5];
  const float* jkW   = (const float*)d_in[6];
  const float* jkb   = (const float*)d_in[7];
  const int*   eidx  = (const int*)d_in[8];
  int N = in_sizes[0] / HID;
  int E = in_sizes[8] / 2;
  const int* src = eidx;
  const int* dst = eidx + E;
  float* out = (float*)d_out;

  // workspace carve (256B aligned)
  char* w = (char*)d_ws;
  auto carve = [&](size_t bytes) -> char* {
    char* p = w; w += (bytes + 255) & ~(size_t)255; return p;
  };
  int Npad = ((N + 63) / 64) * 64;
  int* cnt      = (int*)carve((size_t)N * 4);
  int* offs     = (int*)carve((size_t)(N + 1) * 4);
  int* bsums    = (int*)carve(1024 * 4);
  int* cursor   = (int*)carve((size_t)N * 4);
  int* csr      = (int*)carve((size_t)E * 4);
  ushort* Wlbf  = (ushort*)carve((size_t)3 * HID * HID * 2);
  ushort* Wrbf  = (ushort*)carve((size_t)3 * HID * HID * 2);
  ushort* jkWbf = (ushort*)carve((size_t)HID * 512 * 2);
  ushort* agg   = (ushort*)carve((size_t)Npad * HID * 2);
  ushort* x1    = (ushort*)carve((size_t)Npad * HID * 2);
  ushort* x2    = (ushort*)carve((size_t)Npad * HID * 2);
  ushort* x3    = (ushort*)carve((size_t)Npad * HID * 2);

  hipMemsetAsync(cnt, 0, (size_t)N * 4, stream);
  hipMemsetAsync(cursor, 0, (size_t)N * 4, stream);

  // weights -> bf16
  int nWl = 3 * HID * HID, nJk = HID * 512;
  k_cvt<<<(nWl + 255) / 256, 256, 0, stream>>>(Wl, Wlbf, nWl);
  k_cvt<<<(nWl + 255) / 256, 256, 0, stream>>>(Wr, Wrbf, nWl);
  k_cvt<<<(nJk + 255) / 256, 256, 0, stream>>>(jkW, jkWbf, nJk);

  // CSR build
  k_hist<<<(E + 255) / 256, 256, 0, stream>>>(dst, cnt, E);
  int nb = (N + 1023) / 1024;
  k_scan1<<<nb, 1024, 0, stream>>>(cnt, offs, bsums, N);
  k_scan2<<<1, 64, 0, stream>>>(bsums, nb);
  k_scan3<<<nb, 1024, 0, stream>>>(offs, bsums, N);
  k_bucket<<<(E + 255) / 256, 256, 0, stream>>>(src, dst, offs, cursor, csr, E);

  int aggBlocks = (N + 3) / 4;
  int gemmBlocks = (N + 63) / 64;

  // layer 0 (no residual; xin = emb f32)
  k_aggregate<1><<<aggBlocks, 256, 0, stream>>>(emb, csr, offs, cnt, agg, N);
  k_layer<1, 0><<<gemmBlocks, 256, 0, stream>>>(agg, emb, Wlbf, bl, Wrbf,
                                                gamma, beta, x1, N);
  // layer 1
  k_aggregate<0><<<aggBlocks, 256, 0, stream>>>(x1, csr, offs, cnt, agg, N);
  k_layer<0, 1><<<gemmBlocks, 256, 0, stream>>>(agg, x1, Wlbf + HID * HID, bl + HID,
                                                Wrbf + HID * HID, gamma + HID, beta + HID, x2, N);
  // layer 2
  k_aggregate<0><<<aggBlocks, 256, 0, stream>>>(x2, csr, offs, cnt, agg, N);
  k_layer<0, 1><<<gemmBlocks, 256, 0, stream>>>(agg, x2, Wlbf + 2 * HID * HID, bl + 2 * HID,
                                                Wrbf + 2 * HID * HID, gamma + 2 * HID, beta + 2 * HID, x3, N);
  // jumping knowledge projection
  k_jk<<<gemmBlocks, 256, 0, stream>>>(emb, x1, x2, x3, jkWbf, jkb, out, N);
}

// Round 3
// 815.842 us; speedup vs baseline: 1.3382x; 1.3382x over previous
//
#include <hip/hip_runtime.h>
#include <hip/hip_bf16.h>
#include <stdint.h>

#define HID 128

typedef __attribute__((ext_vector_type(8))) __bf16 bf16x8;
typedef __attribute__((ext_vector_type(4))) float f32x4;

static __device__ __forceinline__ float bf2f(ushort h){
  union { uint u; float f; } c; c.u = ((uint)h) << 16; return c.f;
}
static __device__ __forceinline__ ushort f2bf(float f){
  union { float f; uint u; } c; c.f = f;
  uint u = c.u;
  return (ushort)((u + 0x7fffu + ((u >> 16) & 1u)) >> 16);
}
static __device__ __forceinline__ bf16x8 load8(const ushort* p){
  return *(const bf16x8*)p;
}

// ---------------- f32 -> bf16 convert (weights + emb) ----------------
__global__ void k_cvt(const float* __restrict__ in, ushort* __restrict__ out, int n){
  int i = blockIdx.x * 256 + threadIdx.x;
  if (i < n) out[i] = f2bf(in[i]);
}

// ---------------- CSR build ----------------
__global__ void k_hist(const int* __restrict__ dst, int* __restrict__ cnt, int E){
  int e = blockIdx.x * 256 + threadIdx.x;
  if (e < E) atomicAdd(&cnt[dst[e]], 1);
}

__global__ void k_scan1(const int* __restrict__ cnt, int* __restrict__ offs,
                        int* __restrict__ bsums, int n){
  int gid = blockIdx.x * 1024 + threadIdx.x;
  int v = (gid < n) ? cnt[gid] : 0;
  int lane = threadIdx.x & 63, w = threadIdx.x >> 6;
  int x = v;
  #pragma unroll
  for (int d = 1; d < 64; d <<= 1){ int y = __shfl_up(x, d, 64); if (lane >= d) x += y; }
  __shared__ int tmp[16];
  if (lane == 63) tmp[w] = x;
  __syncthreads();
  if (threadIdx.x < 64){
    int s = (lane < 16) ? tmp[lane] : 0;
    #pragma unroll
    for (int d = 1; d < 16; d <<= 1){ int y = __shfl_up(s, d, 64); if (lane >= d) s += y; }
    if (lane < 16) tmp[lane] = s;
  }
  __syncthreads();
  int base = (w > 0) ? tmp[w - 1] : 0;
  int incl = base + x;
  if (gid < n) offs[gid] = incl - v;
  if (threadIdx.x == 1023) bsums[blockIdx.x] = incl;
}

__global__ void k_scan2(int* bsums, int nb){
  if (threadIdx.x == 0 && blockIdx.x == 0){
    int acc = 0;
    for (int i = 0; i < nb; i++){ int v = bsums[i]; bsums[i] = acc; acc += v; }
  }
}

__global__ void k_scan3(int* __restrict__ offs, const int* __restrict__ bsums, int n){
  int gid = blockIdx.x * 1024 + threadIdx.x;
  if (gid < n) offs[gid] += bsums[blockIdx.x];
}

__global__ void k_bucket(const int* __restrict__ src, const int* __restrict__ dst,
                         const int* __restrict__ offs, int* __restrict__ cursor,
                         int* __restrict__ csr, int E){
  int e = blockIdx.x * 256 + threadIdx.x;
  if (e < E){
    int d = dst[e];
    int p = atomicAdd(&cursor[d], 1);
    csr[offs[d] + p] = src[e];
  }
}

// ---------------- scatter-mean aggregation (wave per node, unroll-8) ----------------
// x: bf16 [N,128]; agg out: bf16. Lane i owns features 2i,2i+1 (one dword).
__global__ __launch_bounds__(256) void k_aggregate(
    const ushort* __restrict__ x, const int* __restrict__ csr,
    const int* __restrict__ offs, const int* __restrict__ cnt,
    ushort* __restrict__ agg, int N){
  int node = blockIdx.x * 4 + (threadIdx.x >> 6);
  int lane = threadIdx.x & 63;
  if (node >= N) return;
  int beg = offs[node], d = cnt[node];
  const int* __restrict__ cp = csr + beg;
  float s0 = 0.f, s1 = 0.f;
  int i = 0;
  for (; i + 8 <= d; i += 8){
    int idx[8];
    #pragma unroll
    for (int u = 0; u < 8; u++) idx[u] = cp[i + u];
    uint v[8];
    #pragma unroll
    for (int u = 0; u < 8; u++)
      v[u] = *(const uint*)(x + (size_t)idx[u] * HID + lane * 2);
    #pragma unroll
    for (int u = 0; u < 8; u++){
      s0 += bf2f((ushort)v[u]);
      s1 += bf2f((ushort)(v[u] >> 16));
    }
  }
  if (i + 4 <= d){
    int idx[4];
    #pragma unroll
    for (int u = 0; u < 4; u++) idx[u] = cp[i + u];
    uint v[4];
    #pragma unroll
    for (int u = 0; u < 4; u++)
      v[u] = *(const uint*)(x + (size_t)idx[u] * HID + lane * 2);
    #pragma unroll
    for (int u = 0; u < 4; u++){
      s0 += bf2f((ushort)v[u]);
      s1 += bf2f((ushort)(v[u] >> 16));
    }
    i += 4;
  }
  for (; i < d; i++){
    int s = cp[i];
    uint v = *(const uint*)(x + (size_t)s * HID + lane * 2);
    s0 += bf2f((ushort)v);
    s1 += bf2f((ushort)(v >> 16));
  }
  float inv = 1.0f / fmaxf((float)d, 1.0f);
  uint o = (uint)f2bf(s0 * inv) | ((uint)f2bf(s1 * inv) << 16);
  *(uint*)(agg + (size_t)node * HID + lane * 2) = o;
}

// ---------------- fused dual-GEMM + bias + LN + ReLU + residual ----------------
// xout = relu(LN(agg@Wl^T + xin@Wr^T + bl)) [+ xin if HAS_RES], all bf16.
// C/D layout (m89): col = lane&15, row = (lane>>4)*4 + reg. A layout: A[m=lane&15][k=quad*8+j].
template<int HAS_RES>
__global__ __launch_bounds__(256) void k_layer(
    const ushort* __restrict__ agg, const ushort* __restrict__ xin,
    const ushort* __restrict__ Wl, const float* __restrict__ bl,
    const ushort* __restrict__ Wr,
    const float* __restrict__ gamma, const float* __restrict__ beta,
    ushort* __restrict__ xout, int N){
  int wv = threadIdx.x >> 6, lane = threadIdx.x & 63;
  int quad = lane >> 4, l16 = lane & 15;
  int rowbase = blockIdx.x * 64 + wv * 16;
  int arow = rowbase + l16;
  if (arow >= N) arow = N - 1;   // clamp: C row m only depends on A row m

  bf16x8 a1[4], a2[4];
  #pragma unroll
  for (int k = 0; k < 4; k++){
    int off = k * 32 + quad * 8;
    a1[k] = load8(agg + (size_t)arow * HID + off);
    a2[k] = load8(xin + (size_t)arow * HID + off);
  }

  f32x4 acc[8];
  #pragma unroll
  for (int jt = 0; jt < 8; jt++){
    int j = jt * 16 + l16;
    f32x4 c = {0.f, 0.f, 0.f, 0.f};
    #pragma unroll
    for (int k = 0; k < 4; k++){
      bf16x8 b = load8(Wl + (size_t)j * HID + k * 32 + quad * 8);
      c = __builtin_amdgcn_mfma_f32_16x16x32_bf16(a1[k], b, c, 0, 0, 0);
    }
    #pragma unroll
    for (int k = 0; k < 4; k++){
      bf16x8 b = load8(Wr + (size_t)j * HID + k * 32 + quad * 8);
      c = __builtin_amdgcn_mfma_f32_16x16x32_bf16(a2[k], b, c, 0, 0, 0);
    }
    float bias = bl[j];
    c[0] += bias; c[1] += bias; c[2] += bias; c[3] += bias;
    acc[jt] = c;
  }

  // LayerNorm over 128 cols per row (quad-local shuffle reduction)
  float s1[4] = {0,0,0,0}, s2[4] = {0,0,0,0};
  #pragma unroll
  for (int jt = 0; jt < 8; jt++){
    #pragma unroll
    for (int r = 0; r < 4; r++){ float v = acc[jt][r]; s1[r] += v; s2[r] += v * v; }
  }
  #pragma unroll
  for (int m = 1; m < 16; m <<= 1){
    #pragma unroll
    for (int r = 0; r < 4; r++){
      s1[r] += __shfl_xor(s1[r], m, 64);
      s2[r] += __shfl_xor(s2[r], m, 64);
    }
  }
  float mu[4], rs[4];
  #pragma unroll
  for (int r = 0; r < 4; r++){
    mu[r] = s1[r] * (1.f / 128.f);
    float var = s2[r] * (1.f / 128.f) - mu[r] * mu[r];
    rs[r] = rsqrtf(var + 1e-5f);
  }

  #pragma unroll
  for (int jt = 0; jt < 8; jt++){
    int col = jt * 16 + l16;
    float g = gamma[col], bb = beta[col];
    #pragma unroll
    for (int r = 0; r < 4; r++){
      int row = rowbase + quad * 4 + r;
      if (row < N){
        float v = (acc[jt][r] - mu[r]) * rs[r] * g + bb;
        v = fmaxf(v, 0.f);
        if (HAS_RES) v += bf2f(xin[(size_t)row * HID + col]);
        xout[(size_t)row * HID + col] = f2bf(v);
      }
    }
  }
}

// ---------------- JK: out = [emb,x1,x2,x3] @ jkW^T + jkb  (out: float32) ----------------
__global__ __launch_bounds__(256) void k_jk(
    const ushort* __restrict__ emb, const ushort* __restrict__ x1,
    const ushort* __restrict__ x2, const ushort* __restrict__ x3,
    const ushort* __restrict__ jkW, const float* __restrict__ jkb,
    float* __restrict__ out, int N){
  int wv = threadIdx.x >> 6, lane = threadIdx.x & 63;
  int quad = lane >> 4, l16 = lane & 15;
  int rowbase = blockIdx.x * 64 + wv * 16;
  int arow = rowbase + l16;
  if (arow >= N) arow = N - 1;

  const ushort* srcs[4] = {emb, x1, x2, x3};
  bf16x8 a[16];
  #pragma unroll
  for (int kk = 0; kk < 16; kk++){
    const ushort* s = srcs[kk >> 2];
    a[kk] = load8(s + (size_t)arow * HID + (kk & 3) * 32 + quad * 8);
  }
  #pragma unroll
  for (int jt = 0; jt < 8; jt++){
    int j = jt * 16 + l16;
    f32x4 c = {0.f, 0.f, 0.f, 0.f};
    #pragma unroll
    for (int kk = 0; kk < 16; kk++){
      bf16x8 b = load8(jkW + (size_t)j * 512 + kk * 32 + quad * 8);
      c = __builtin_amdgcn_mfma_f32_16x16x32_bf16(a[kk], b, c, 0, 0, 0);
    }
    float bias = jkb[j];
    #pragma unroll
    for (int r = 0; r < 4; r++){
      int row = rowbase + quad * 4 + r;
      if (row < N)
        out[(size_t)row * HID + jt * 16 + l16] = c[r] + bias;
    }
  }
}

extern "C" void kernel_launch(void* const* d_in, const int* in_sizes, int n_in,
                              void* d_out, int out_size, void* d_ws, size_t ws_size,
                              hipStream_t stream){
  const float* emb   = (const float*)d_in[0];
  const float* Wl    = (const float*)d_in[1];
  const float* bl    = (const float*)d_in[2];
  const float* Wr    = (const float*)d_in[3];
  const float* gamma = (const float*)d_in[4];
  const float* beta  = (const float*)d_in[5];
  const float* jkW   = (const float*)d_in[6];
  const float* jkb   = (const float*)d_in[7];
  const int*   eidx  = (const int*)d_in[8];
  int N = in_sizes[0] / HID;
  int E = in_sizes[8] / 2;
  const int* src = eidx;
  const int* dst = eidx + E;
  float* out = (float*)d_out;

  // workspace carve (256B aligned)
  char* w = (char*)d_ws;
  auto carve = [&](size_t bytes) -> char* {
    char* p = w; w += (bytes + 255) & ~(size_t)255; return p;
  };
  int Npad = ((N + 63) / 64) * 64;
  int* cnt      = (int*)carve((size_t)N * 4);
  int* offs     = (int*)carve((size_t)(N + 1) * 4);
  int* bsums    = (int*)carve(1024 * 4);
  int* cursor   = (int*)carve((size_t)N * 4);
  int* csr      = (int*)carve((size_t)E * 4);
  ushort* Wlbf  = (ushort*)carve((size_t)3 * HID * HID * 2);
  ushort* Wrbf  = (ushort*)carve((size_t)3 * HID * HID * 2);
  ushort* jkWbf = (ushort*)carve((size_t)HID * 512 * 2);
  ushort* embbf = (ushort*)carve((size_t)Npad * HID * 2);
  ushort* agg   = (ushort*)carve((size_t)Npad * HID * 2);
  ushort* x1    = (ushort*)carve((size_t)Npad * HID * 2);
  ushort* x2    = (ushort*)carve((size_t)Npad * HID * 2);
  ushort* x3    = (ushort*)carve((size_t)Npad * HID * 2);

  hipMemsetAsync(cnt, 0, (size_t)N * 4, stream);
  hipMemsetAsync(cursor, 0, (size_t)N * 4, stream);

  // f32 -> bf16: weights + emb
  int nWl = 3 * HID * HID, nJk = HID * 512, nEmb = N * HID;
  k_cvt<<<(nWl + 255) / 256, 256, 0, stream>>>(Wl, Wlbf, nWl);
  k_cvt<<<(nWl + 255) / 256, 256, 0, stream>>>(Wr, Wrbf, nWl);
  k_cvt<<<(nJk + 255) / 256, 256, 0, stream>>>(jkW, jkWbf, nJk);
  k_cvt<<<(nEmb + 255) / 256, 256, 0, stream>>>(emb, embbf, nEmb);

  // CSR build
  k_hist<<<(E + 255) / 256, 256, 0, stream>>>(dst, cnt, E);
  int nb = (N + 1023) / 1024;
  k_scan1<<<nb, 1024, 0, stream>>>(cnt, offs, bsums, N);
  k_scan2<<<1, 64, 0, stream>>>(bsums, nb);
  k_scan3<<<nb, 1024, 0, stream>>>(offs, bsums, N);
  k_bucket<<<(E + 255) / 256, 256, 0, stream>>>(src, dst, offs, cursor, csr, E);

  int aggBlocks = (N + 3) / 4;
  int gemmBlocks = (N + 63) / 64;

  // layer 0 (no residual)
  k_aggregate<<<aggBlocks, 256, 0, stream>>>(embbf, csr, offs, cnt, agg, N);
  k_layer<0><<<gemmBlocks, 256, 0, stream>>>(agg, embbf, Wlbf, bl, Wrbf, gamma, beta, x1, N);
  // layer 1
  k_aggregate<<<aggBlocks, 256, 0, stream>>>(x1, csr, offs, cnt, agg, N);
  k_layer<1><<<gemmBlocks, 256, 0, stream>>>(agg, x1, Wlbf + HID * HID, bl + HID,
                                             Wrbf + HID * HID, gamma + HID, beta + HID, x2, N);
  // layer 2
  k_aggregate<<<aggBlocks, 256, 0, stream>>>(x2, csr, offs, cnt, agg, N);
  k_layer<1><<<gemmBlocks, 256, 0, stream>>>(agg, x2, Wlbf + 2 * HID * HID, bl + 2 * HID,
                                             Wrbf + 2 * HID * HID, gamma + 2 * HID, beta + 2 * HID, x3, N);
  // jumping knowledge projection
  k_jk<<<gemmBlocks, 256, 0, stream>>>(embbf, x1, x2, x3, jkWbf, jkb, out, N);
}

// Round 4
// 631.473 us; speedup vs baseline: 1.7289x; 1.2920x over previous
//
#include <hip/hip_runtime.h>
#include <hip/hip_bf16.h>
#include <stdint.h>

#define HID 128

typedef __attribute__((ext_vector_type(8))) __bf16 bf16x8;
typedef __attribute__((ext_vector_type(4))) float f32x4;

static __device__ __forceinline__ float bf2f(ushort h){
  union { uint u; float f; } c; c.u = ((uint)h) << 16; return c.f;
}
static __device__ __forceinline__ ushort f2bf(float f){
  union { float f; uint u; } c; c.f = f;
  uint u = c.u;
  return (ushort)((u + 0x7fffu + ((u >> 16) & 1u)) >> 16);
}
static __device__ __forceinline__ bf16x8 load8(const ushort* p){
  return *(const bf16x8*)p;
}

// ---------------- f32 -> bf16 convert (emb) ----------------
__global__ void k_cvt(const float* __restrict__ in, ushort* __restrict__ out, int n){
  int i = blockIdx.x * 256 + threadIdx.x;
  if (i < n) out[i] = f2bf(in[i]);
}

// ---- layer weights f32 -> bf16 frag-major: [layer][kt4][mat2][jt8][lane64][e8] ----
__global__ void k_cvtw(const float* __restrict__ Wl, const float* __restrict__ Wr,
                       ushort* __restrict__ outF, int total){
  int o = blockIdx.x * 256 + threadIdx.x;
  if (o >= total) return;
  int layer = o >> 15;
  int r = o & 32767;
  int e    = r & 7;
  int lane = (r >> 3) & 63;
  int jt   = (r >> 9) & 7;
  int mat  = (r >> 12) & 1;
  int kt   = r >> 13;
  int l16 = lane & 15, quad = lane >> 4;
  int j = jt * 16 + l16;
  int k = kt * 32 + quad * 8 + e;
  const float* W = mat ? Wr : Wl;
  outF[o] = f2bf(W[layer * 16384 + j * 128 + k]);
}

// ---- jk weights f32 -> bf16 frag-major: [kt16][jt8][lane64][e8] ----
__global__ void k_cvtjk(const float* __restrict__ jkW, ushort* __restrict__ outF){
  int o = blockIdx.x * 256 + threadIdx.x;   // total 65536
  int e    = o & 7;
  int lane = (o >> 3) & 63;
  int jt   = (o >> 9) & 7;
  int kt   = o >> 12;
  int l16 = lane & 15, quad = lane >> 4;
  int j = jt * 16 + l16;
  int k = kt * 32 + quad * 8 + e;
  outF[o] = f2bf(jkW[j * 512 + k]);
}

// ---------------- CSR build ----------------
__global__ void k_hist(const int* __restrict__ dst, int* __restrict__ cnt, int E){
  int e = blockIdx.x * 256 + threadIdx.x;
  if (e < E) atomicAdd(&cnt[dst[e]], 1);
}

__global__ void k_scan1(const int* __restrict__ cnt, int* __restrict__ offs,
                        int* __restrict__ bsums, int n){
  int gid = blockIdx.x * 1024 + threadIdx.x;
  int v = (gid < n) ? cnt[gid] : 0;
  int lane = threadIdx.x & 63, w = threadIdx.x >> 6;
  int x = v;
  #pragma unroll
  for (int d = 1; d < 64; d <<= 1){ int y = __shfl_up(x, d, 64); if (lane >= d) x += y; }
  __shared__ int tmp[16];
  if (lane == 63) tmp[w] = x;
  __syncthreads();
  if (threadIdx.x < 64){
    int s = (lane < 16) ? tmp[lane] : 0;
    #pragma unroll
    for (int d = 1; d < 16; d <<= 1){ int y = __shfl_up(s, d, 64); if (lane >= d) s += y; }
    if (lane < 16) tmp[lane] = s;
  }
  __syncthreads();
  int base = (w > 0) ? tmp[w - 1] : 0;
  int incl = base + x;
  if (gid < n) offs[gid] = incl - v;
  if (threadIdx.x == 1023) bsums[blockIdx.x] = incl;
}

__global__ void k_scan2(int* bsums, int nb){
  if (threadIdx.x == 0 && blockIdx.x == 0){
    int acc = 0;
    for (int i = 0; i < nb; i++){ int v = bsums[i]; bsums[i] = acc; acc += v; }
  }
}

__global__ void k_scan3(int* __restrict__ offs, const int* __restrict__ bsums, int n){
  int gid = blockIdx.x * 1024 + threadIdx.x;
  if (gid < n) offs[gid] += bsums[blockIdx.x];
}

__global__ void k_bucket(const int* __restrict__ src, const int* __restrict__ dst,
                         const int* __restrict__ offs, int* __restrict__ cursor,
                         int* __restrict__ csr, int E){
  int e = blockIdx.x * 256 + threadIdx.x;
  if (e < E){
    int d = dst[e];
    int p = atomicAdd(&cursor[d], 1);
    csr[offs[d] + p] = src[e];
  }
}

// ---------------- scatter-mean aggregation (wave per node, unroll-8) ----------------
__global__ __launch_bounds__(256) void k_aggregate(
    const ushort* __restrict__ x, const int* __restrict__ csr,
    const int* __restrict__ offs, const int* __restrict__ cnt,
    ushort* __restrict__ agg, int N){
  int node = blockIdx.x * 4 + (threadIdx.x >> 6);
  int lane = threadIdx.x & 63;
  if (node >= N) return;
  int beg = offs[node], d = cnt[node];
  const int* __restrict__ cp = csr + beg;
  float s0 = 0.f, s1 = 0.f;
  int i = 0;
  for (; i + 8 <= d; i += 8){
    int idx[8];
    #pragma unroll
    for (int u = 0; u < 8; u++) idx[u] = cp[i + u];
    uint v[8];
    #pragma unroll
    for (int u = 0; u < 8; u++)
      v[u] = *(const uint*)(x + (size_t)idx[u] * HID + lane * 2);
    #pragma unroll
    for (int u = 0; u < 8; u++){
      s0 += bf2f((ushort)v[u]);
      s1 += bf2f((ushort)(v[u] >> 16));
    }
  }
  if (i + 4 <= d){
    int idx[4];
    #pragma unroll
    for (int u = 0; u < 4; u++) idx[u] = cp[i + u];
    uint v[4];
    #pragma unroll
    for (int u = 0; u < 4; u++)
      v[u] = *(const uint*)(x + (size_t)idx[u] * HID + lane * 2);
    #pragma unroll
    for (int u = 0; u < 4; u++){
      s0 += bf2f((ushort)v[u]);
      s1 += bf2f((ushort)(v[u] >> 16));
    }
    i += 4;
  }
  for (; i < d; i++){
    int s = cp[i];
    uint v = *(const uint*)(x + (size_t)s * HID + lane * 2);
    s0 += bf2f((ushort)v);
    s1 += bf2f((ushort)(v >> 16));
  }
  float inv = 1.0f / fmaxf((float)d, 1.0f);
  uint o = (uint)f2bf(s0 * inv) | ((uint)f2bf(s1 * inv) << 16);
  *(uint*)(agg + (size_t)node * HID + lane * 2) = o;
}

// ---------------- fused dual-GEMM + bias + LN + ReLU + residual ----------------
// 128 rows/block (4 waves x 2 rowtiles). B staged via 16KB LDS in frag-major order.
// C/D layout (m89): col = lane&15, row = (lane>>4)*4 + reg.
template<int HAS_RES>
__global__ __launch_bounds__(256) void k_layer(
    const ushort* __restrict__ agg, const ushort* __restrict__ xin,
    const ushort* __restrict__ Wf,     // [kt4][mat2][jt8][lane64][8] bf16
    const float* __restrict__ bl, const float* __restrict__ gamma,
    const float* __restrict__ beta,
    ushort* __restrict__ xout, int N){
  __shared__ ushort sB[8192];
  int tid = threadIdx.x;
  int wv = tid >> 6, lane = tid & 63;
  int quad = lane >> 4, l16 = lane & 15;
  int rowbase = blockIdx.x * 128 + wv * 32;
  int r0 = rowbase + l16;      if (r0 >= N) r0 = N - 1;
  int r1 = rowbase + 16 + l16; if (r1 >= N) r1 = N - 1;

  f32x4 acc[2][8];
  #pragma unroll
  for (int jt = 0; jt < 8; jt++){
    float b = bl[jt * 16 + l16];
    f32x4 c = {b, b, b, b};
    acc[0][jt] = c; acc[1][jt] = c;
  }

  #pragma unroll
  for (int kt = 0; kt < 4; kt++){
    int ao = kt * 32 + quad * 8;
    bf16x8 a10 = load8(agg + (size_t)r0 * HID + ao);
    bf16x8 a11 = load8(agg + (size_t)r1 * HID + ao);
    bf16x8 a20 = load8(xin + (size_t)r0 * HID + ao);
    bf16x8 a21 = load8(xin + (size_t)r1 * HID + ao);
    __syncthreads();
    const ushort* src = Wf + kt * 8192;
    #pragma unroll
    for (int i = 0; i < 4; i++){
      int c = i * 256 + tid;
      *(bf16x8*)(sB + c * 8) = load8(src + c * 8);
    }
    __syncthreads();
    #pragma unroll
    for (int jt = 0; jt < 8; jt++){
      bf16x8 bL = load8(sB + (jt * 64 + lane) * 8);
      bf16x8 bR = load8(sB + ((8 + jt) * 64 + lane) * 8);
      acc[0][jt] = __builtin_amdgcn_mfma_f32_16x16x32_bf16(a10, bL, acc[0][jt], 0, 0, 0);
      acc[1][jt] = __builtin_amdgcn_mfma_f32_16x16x32_bf16(a11, bL, acc[1][jt], 0, 0, 0);
      acc[0][jt] = __builtin_amdgcn_mfma_f32_16x16x32_bf16(a20, bR, acc[0][jt], 0, 0, 0);
      acc[1][jt] = __builtin_amdgcn_mfma_f32_16x16x32_bf16(a21, bR, acc[1][jt], 0, 0, 0);
    }
  }

  #pragma unroll
  for (int rt = 0; rt < 2; rt++){
    float s1[4] = {0,0,0,0}, s2[4] = {0,0,0,0};
    #pragma unroll
    for (int jt = 0; jt < 8; jt++){
      #pragma unroll
      for (int r = 0; r < 4; r++){ float v = acc[rt][jt][r]; s1[r] += v; s2[r] += v * v; }
    }
    #pragma unroll
    for (int m = 1; m < 16; m <<= 1){
      #pragma unroll
      for (int r = 0; r < 4; r++){
        s1[r] += __shfl_xor(s1[r], m, 64);
        s2[r] += __shfl_xor(s2[r], m, 64);
      }
    }
    float mu[4], rs[4];
    #pragma unroll
    for (int r = 0; r < 4; r++){
      mu[r] = s1[r] * (1.f / 128.f);
      float var = s2[r] * (1.f / 128.f) - mu[r] * mu[r];
      rs[r] = rsqrtf(var + 1e-5f);
    }
    #pragma unroll
    for (int jt = 0; jt < 8; jt++){
      int col = jt * 16 + l16;
      float g = gamma[col], bb = beta[col];
      #pragma unroll
      for (int r = 0; r < 4; r++){
        int row = rowbase + rt * 16 + quad * 4 + r;
        if (row < N){
          float v = (acc[rt][jt][r] - mu[r]) * rs[r] * g + bb;
          v = fmaxf(v, 0.f);
          if (HAS_RES) v += bf2f(xin[(size_t)row * HID + col]);
          xout[(size_t)row * HID + col] = f2bf(v);
        }
      }
    }
  }
}

// ---------------- JK: out = [emb,x1,x2,x3] @ jkW^T + jkb  (out f32) ----------------
// K=512 staged in 8 x 16KB LDS stages (2 K32-tiles per stage).
__global__ __launch_bounds__(256) void k_jk(
    const ushort* __restrict__ emb, const ushort* __restrict__ x1,
    const ushort* __restrict__ x2, const ushort* __restrict__ x3,
    const ushort* __restrict__ Wf,   // [kt16][jt8][lane64][8] bf16
    const float* __restrict__ jkb, float* __restrict__ out, int N){
  __shared__ ushort sB[8192];
  int tid = threadIdx.x;
  int wv = tid >> 6, lane = tid & 63;
  int quad = lane >> 4, l16 = lane & 15;
  int rowbase = blockIdx.x * 128 + wv * 32;
  int r0 = rowbase + l16;      if (r0 >= N) r0 = N - 1;
  int r1 = rowbase + 16 + l16; if (r1 >= N) r1 = N - 1;

  f32x4 acc[2][8];
  #pragma unroll
  for (int jt = 0; jt < 8; jt++){
    float b = jkb[jt * 16 + l16];
    f32x4 c = {b, b, b, b};
    acc[0][jt] = c; acc[1][jt] = c;
  }

  const ushort* srcs[4] = {emb, x1, x2, x3};
  #pragma unroll
  for (int st = 0; st < 8; st++){
    int kt0 = st * 2, kt1 = st * 2 + 1;
    const ushort* sp0 = srcs[kt0 >> 2];
    const ushort* sp1 = srcs[kt1 >> 2];
    int ao0 = (kt0 & 3) * 32 + quad * 8;
    int ao1 = (kt1 & 3) * 32 + quad * 8;
    bf16x8 aA0 = load8(sp0 + (size_t)r0 * HID + ao0);
    bf16x8 aA1 = load8(sp0 + (size_t)r1 * HID + ao0);
    bf16x8 aB0 = load8(sp1 + (size_t)r0 * HID + ao1);
    bf16x8 aB1 = load8(sp1 + (size_t)r1 * HID + ao1);
    __syncthreads();
    const ushort* src = Wf + st * 8192;
    #pragma unroll
    for (int i = 0; i < 4; i++){
      int c = i * 256 + tid;
      *(bf16x8*)(sB + c * 8) = load8(src + c * 8);
    }
    __syncthreads();
    #pragma unroll
    for (int jt = 0; jt < 8; jt++){
      bf16x8 b0 = load8(sB + (jt * 64 + lane) * 8);
      bf16x8 b1 = load8(sB + ((8 + jt) * 64 + lane) * 8);
      acc[0][jt] = __builtin_amdgcn_mfma_f32_16x16x32_bf16(aA0, b0, acc[0][jt], 0, 0, 0);
      acc[1][jt] = __builtin_amdgcn_mfma_f32_16x16x32_bf16(aA1, b0, acc[1][jt], 0, 0, 0);
      acc[0][jt] = __builtin_amdgcn_mfma_f32_16x16x32_bf16(aB0, b1, acc[0][jt], 0, 0, 0);
      acc[1][jt] = __builtin_amdgcn_mfma_f32_16x16x32_bf16(aB1, b1, acc[1][jt], 0, 0, 0);
    }
  }

  #pragma unroll
  for (int rt = 0; rt < 2; rt++){
    #pragma unroll
    for (int jt = 0; jt < 8; jt++){
      #pragma unroll
      for (int r = 0; r < 4; r++){
        int row = rowbase + rt * 16 + quad * 4 + r;
        if (row < N)
          out[(size_t)row * HID + jt * 16 + l16] = acc[rt][jt][r];
      }
    }
  }
}

extern "C" void kernel_launch(void* const* d_in, const int* in_sizes, int n_in,
                              void* d_out, int out_size, void* d_ws, size_t ws_size,
                              hipStream_t stream){
  const float* emb   = (const float*)d_in[0];
  const float* Wl    = (const float*)d_in[1];
  const float* bl    = (const float*)d_in[2];
  const float* Wr    = (const float*)d_in[3];
  const float* gamma = (const float*)d_in[4];
  const float* beta  = (const float*)d_in[5];
  const float* jkW   = (const float*)d_in[6];
  const float* jkb   = (const float*)d_in[7];
  const int*   eidx  = (const int*)d_in[8];
  int N = in_sizes[0] / HID;
  int E = in_sizes[8] / 2;
  const int* src = eidx;
  const int* dst = eidx + E;
  float* out = (float*)d_out;

  // workspace carve (256B aligned)
  char* w = (char*)d_ws;
  auto carve = [&](size_t bytes) -> char* {
    char* p = w; w += (bytes + 255) & ~(size_t)255; return p;
  };
  int Npad = ((N + 127) / 128) * 128;
  int* cnt      = (int*)carve((size_t)N * 4);
  int* offs     = (int*)carve((size_t)(N + 1) * 4);
  int* bsums    = (int*)carve(1024 * 4);
  int* cursor   = (int*)carve((size_t)N * 4);
  int* csr      = (int*)carve((size_t)E * 4);
  ushort* Wfrag = (ushort*)carve((size_t)3 * 32768 * 2);
  ushort* jkWf  = (ushort*)carve((size_t)65536 * 2);
  ushort* embbf = (ushort*)carve((size_t)Npad * HID * 2);
  ushort* agg   = (ushort*)carve((size_t)Npad * HID * 2);
  ushort* x1    = (ushort*)carve((size_t)Npad * HID * 2);
  ushort* x2    = (ushort*)carve((size_t)Npad * HID * 2);
  ushort* x3    = (ushort*)carve((size_t)Npad * HID * 2);

  hipMemsetAsync(cnt, 0, (size_t)N * 4, stream);
  hipMemsetAsync(cursor, 0, (size_t)N * 4, stream);

  // weight transforms + emb cast
  int nEmb = N * HID;
  k_cvtw<<<(3 * 32768 + 255) / 256, 256, 0, stream>>>(Wl, Wr, Wfrag, 3 * 32768);
  k_cvtjk<<<65536 / 256, 256, 0, stream>>>(jkW, jkWf);
  k_cvt<<<(nEmb + 255) / 256, 256, 0, stream>>>(emb, embbf, nEmb);

  // CSR build
  k_hist<<<(E + 255) / 256, 256, 0, stream>>>(dst, cnt, E);
  int nb = (N + 1023) / 1024;
  k_scan1<<<nb, 1024, 0, stream>>>(cnt, offs, bsums, N);
  k_scan2<<<1, 64, 0, stream>>>(bsums, nb);
  k_scan3<<<nb, 1024, 0, stream>>>(offs, bsums, N);
  k_bucket<<<(E + 255) / 256, 256, 0, stream>>>(src, dst, offs, cursor, csr, E);

  int aggBlocks = (N + 3) / 4;
  int gemmBlocks = (N + 127) / 128;

  // layer 0 (no residual)
  k_aggregate<<<aggBlocks, 256, 0, stream>>>(embbf, csr, offs, cnt, agg, N);
  k_layer<0><<<gemmBlocks, 256, 0, stream>>>(agg, embbf, Wfrag, bl, gamma, beta, x1, N);
  // layer 1
  k_aggregate<<<aggBlocks, 256, 0, stream>>>(x1, csr, offs, cnt, agg, N);
  k_layer<1><<<gemmBlocks, 256, 0, stream>>>(agg, x1, Wfrag + 32768, bl + HID,
                                             gamma + HID, beta + HID, x2, N);
  // layer 2
  k_aggregate<<<aggBlocks, 256, 0, stream>>>(x2, csr, offs, cnt, agg, N);
  k_layer<1><<<gemmBlocks, 256, 0, stream>>>(agg, x2, Wfrag + 2 * 32768, bl + 2 * HID,
                                             gamma + 2 * HID, beta + 2 * HID, x3, N);
  // jumping knowledge projection
  k_jk<<<gemmBlocks, 256, 0, stream>>>(embbf, x1, x2, x3, jkWf, jkb, out, N);
}